// Round 5
// baseline (430.357 us; speedup 1.0000x reference)
//
#include <hip/hip_runtime.h>
#include <hip/hip_bf16.h>

#define ENC_DIM 2048
#define DEC_DIM 512
#define ATT_DIM 512
#define BATCH   256
#define NPIX    196
#define MROWS   (BATCH * NPIX)          // 50176 = 392 * 128
#define KT_N    64                      // K tiles of 32
#define BUFSZ   24576                   // A 16K fp32 + B 8K bf16

typedef __attribute__((ext_vector_type(8)))  short short8;
typedef __attribute__((ext_vector_type(4)))  float f32x4;

typedef const __attribute__((address_space(1))) unsigned int gu32;
typedef __attribute__((address_space(3))) unsigned int lu32;

__device__ __forceinline__ short f2bf(float x) {
    unsigned u = __builtin_bit_cast(unsigned, x);
    unsigned r = (u + 0x7FFFu + ((u >> 16) & 1u)) >> 16;
    return (short)r;
}
__device__ __forceinline__ unsigned pkbf(float a, float b) {
    unsigned r;
    asm("v_cvt_pk_bf16_f32 %0, %1, %2" : "=v"(r) : "v"(a), "v"(b));
    return r;
}

// ---------------------------------------------------------------------------
// prep: blocks [0,256)   -> att2pb[b][a] = b_enc[a] + b_dec[a] + h[b]·W_dec[:,a]
//       blocks [256,768) -> pack W_enc into bf16 16x16x32 B-fragment order:
//         chunk c = (nt*64 + kt)*64 + l  (nt: 16-col tile, kt: 32-K tile)
//         elem j = W_enc[kt*32 + ((l>>4)&3)*8 + j][nt*16 + (l&15)]
// ---------------------------------------------------------------------------
__global__ __launch_bounds__(256) void bahdanau_prep(
    const float* __restrict__ dec_h, const float* __restrict__ W_enc,
    const float* __restrict__ b_enc, const float* __restrict__ W_dec,
    const float* __restrict__ b_dec,
    float* __restrict__ att2pb, short* __restrict__ Wpack)
{
    int blk = blockIdx.x;
    if (blk < BATCH) {
        __shared__ float hs[DEC_DIM];
        int b = blk;
        for (int i = threadIdx.x; i < DEC_DIM; i += 256) hs[i] = dec_h[b * DEC_DIM + i];
        __syncthreads();
        for (int a = threadIdx.x; a < ATT_DIM; a += 256) {
            float s = 0.f;
            #pragma unroll 8
            for (int d = 0; d < DEC_DIM; ++d) s += hs[d] * W_dec[d * ATT_DIM + a];
            att2pb[b * ATT_DIM + a] = s + b_dec[a] + b_enc[a];
        }
    } else {
        int c  = (blk - BATCH) * 256 + threadIdx.x;   // 0 .. 131071
        int l  = c & 63;
        int kt = (c >> 6) & 63;
        int nt = c >> 12;
        int n     = nt * 16 + (l & 15);
        int kbase = kt * 32 + ((l >> 4) & 3) * 8;
        short8 v;
        #pragma unroll
        for (int j = 0; j < 8; ++j) v[j] = f2bf(W_enc[(kbase + j) * ATT_DIM + n]);
        *reinterpret_cast<short8*>(Wpack + (size_t)c * 8) = v;
    }
}

// ---------------------------------------------------------------------------
// gemm: grid 1568 = 392 mt x 4 nc; 256 thr, 4 waves (2 wm x 2 wn).
// Tile 128x128; wave 64x64 = 4x4 frags of 16x16x32 bf16, acc 64 AGPRs.
// LDS: THREE 24KB buffers. A staged fp32 in FRAGMENT ORDER via
// global_load_lds w=16 (per-lane source swizzle, linear LDS dest) -> all
// frag ds_read_b128 are contiguous-16B/lane = conflict-free. B staged from
// pre-packed Wpack (frag order). 3-deep pipeline, counted vmcnt (never
// drain mid-loop): wait vmcnt(12) -> barrier -> compute -> lgkm(0) ->
// barrier -> stage(t+3). A converted fp32->bf16 post-ds_read (cvt_pk).
// Epilogue folds relu(att1+att2)·w_full -> spart[nc][row].
// ---------------------------------------------------------------------------
__global__ __launch_bounds__(256, 2) void bahdanau_gemm(
    const float* __restrict__ enc, const float* __restrict__ w_full,
    const float* __restrict__ att2pb, const short* __restrict__ Wpack,
    float* __restrict__ spart)
{
    __shared__ __align__(16) char lds[3 * BUFSZ];
    __shared__ float redm[2][128];

    const int wg = blockIdx.x;                      // 1568 = 49*32
    const int mt = ((wg >> 5) << 3) | (wg & 7);     // 4 nc-sharers -> same XCD
    const int nc = (wg >> 3) & 3;

    const int tid  = threadIdx.x;
    const int lane = tid & 63;
    const int wid  = tid >> 6;
    const int wm   = wid >> 1;
    const int wn   = wid & 1;

    // ---- A source offsets: chunk ca = tid+256s -> (rt=ca>>7, h=(ca>>6)&1, l=ca&63)
    //      holds floats k=(l>>4)*8 + h*4 .. +3 of row rt*16+(l&15)
    size_t aoff[4];
    #pragma unroll
    for (int s = 0; s < 4; ++s) {
        int ca = tid + 256 * s;
        int l = ca & 63, h = (ca >> 6) & 1, rt = ca >> 7;
        aoff[s] = (size_t)(mt * 128 + rt * 16 + (l & 15)) * ENC_DIM
                + ((l >> 4) & 3) * 8 + h * 4;
    }
    // ---- B source offsets: chunk cb = tid+256s -> (f=cb>>6, l=cb&63)
    size_t boff[2];
    #pragma unroll
    for (int s = 0; s < 2; ++s) {
        int cb = tid + 256 * s;
        int f = cb >> 6, l = cb & 63;
        boff[s] = (size_t)(nc * 8 + f) * 32768 + (size_t)l * 8;   // + kt*512
    }

    f32x4 acc[4][4];
    #pragma unroll
    for (int a = 0; a < 4; ++a)
        #pragma unroll
        for (int c = 0; c < 4; ++c)
            #pragma unroll
            for (int r = 0; r < 4; ++r) acc[a][c][r] = 0.f;

    auto STAGE = [&](char* base, int kt) {
        #pragma unroll
        for (int s = 0; s < 4; ++s)
            __builtin_amdgcn_global_load_lds((gu32*)(enc + aoff[s] + kt * 32),
                                             (lu32*)(base + (tid + 256 * s) * 16), 16, 0, 0);
        #pragma unroll
        for (int s = 0; s < 2; ++s)
            __builtin_amdgcn_global_load_lds((gu32*)(Wpack + boff[s] + (size_t)kt * 512),
                                             (lu32*)(base + 16384 + (tid + 256 * s) * 16), 16, 0, 0);
    };

    auto COMPUTE = [&](const char* base) {
        short8 af[4], bf[4];
        #pragma unroll
        for (int rw = 0; rw < 4; ++rw) {
            int rt = wm * 4 + rw;
            float4 lo = *reinterpret_cast<const float4*>(base + ((rt * 2 + 0) * 64 + lane) * 16);
            float4 hi = *reinterpret_cast<const float4*>(base + ((rt * 2 + 1) * 64 + lane) * 16);
            union { short8 s; unsigned u[4]; } fr;
            fr.u[0] = pkbf(lo.x, lo.y); fr.u[1] = pkbf(lo.z, lo.w);
            fr.u[2] = pkbf(hi.x, hi.y); fr.u[3] = pkbf(hi.z, hi.w);
            af[rw] = fr.s;
        }
        #pragma unroll
        for (int ct = 0; ct < 4; ++ct)
            bf[ct] = *reinterpret_cast<const short8*>(base + 16384 + ((wn * 4 + ct) * 64 + lane) * 16);
        #pragma unroll
        for (int rw = 0; rw < 4; ++rw)
            #pragma unroll
            for (int ct = 0; ct < 4; ++ct)
                acc[rw][ct] = __builtin_amdgcn_mfma_f32_16x16x32_bf16(af[rw], bf[ct], acc[rw][ct], 0, 0, 0);
    };

    char* p0 = lds;
    char* p1 = lds + BUFSZ;
    char* p2 = lds + 2 * BUFSZ;

    // prologue: 3 tiles in flight (18 glds per wave)
    STAGE(p0, 0);
    STAGE(p1, 1);
    STAGE(p2, 2);

    for (int t = 0; t < KT_N - 3; ++t) {            // t = 0..60
        asm volatile("s_waitcnt vmcnt(12)" ::: "memory");   // own S(t) landed
        __builtin_amdgcn_s_barrier();                        // everyone's S(t) landed
        COMPUTE(p0);
        asm volatile("s_waitcnt lgkmcnt(0)" ::: "memory");   // my reads of p0 done
        __builtin_amdgcn_s_barrier();                        // all waves done reading p0
        STAGE(p0, t + 3);                                    // overwrite p0 with tile t+3
        char* tmp = p0; p0 = p1; p1 = p2; p2 = tmp;
    }
    // t = 61: S(62),S(63) outstanding = 12
    asm volatile("s_waitcnt vmcnt(12)" ::: "memory");
    __builtin_amdgcn_s_barrier();
    COMPUTE(p0);
    { char* tmp = p0; p0 = p1; p1 = p2; p2 = tmp; }
    // t = 62: S(63) outstanding = 6
    asm volatile("s_waitcnt vmcnt(6)" ::: "memory");
    __builtin_amdgcn_s_barrier();
    COMPUTE(p0);
    { char* tmp = p0; p0 = p1; p1 = p2; p2 = tmp; }
    // t = 63: drain
    asm volatile("s_waitcnt vmcnt(0)" ::: "memory");
    __builtin_amdgcn_s_barrier();
    COMPUTE(p0);

    // ---- epilogue: relu(att1 + att2)·w_full -> per-row partials over 64 cols
    float srow[16];
    #pragma unroll
    for (int i = 0; i < 16; ++i) srow[i] = 0.f;
    #pragma unroll
    for (int ct = 0; ct < 4; ++ct) {
        int col  = nc * 128 + wn * 64 + ct * 16 + (lane & 15);
        float wf = w_full[col];
        #pragma unroll
        for (int rt = 0; rt < 4; ++rt) {
            #pragma unroll
            for (int r = 0; r < 4; ++r) {
                unsigned grow = mt * 128 + wm * 64 + rt * 16 + (lane >> 4) * 4 + r;
                unsigned bb   = grow / NPIX;
                float v = acc[rt][ct][r] + att2pb[bb * ATT_DIM + col];
                srow[rt * 4 + r] += fmaxf(v, 0.f) * wf;
            }
        }
    }
    #pragma unroll
    for (int i = 0; i < 16; ++i) {
        float v = srow[i];
        v += __shfl_xor(v, 1);
        v += __shfl_xor(v, 2);
        v += __shfl_xor(v, 4);
        v += __shfl_xor(v, 8);
        srow[i] = v;
    }
    if ((lane & 15) == 0) {
        #pragma unroll
        for (int rt = 0; rt < 4; ++rt)
            #pragma unroll
            for (int r = 0; r < 4; ++r)
                redm[wn][wm * 64 + rt * 16 + (lane >> 4) * 4 + r] = srow[rt * 4 + r];
    }
    __syncthreads();
    if (tid < 128)
        spart[(size_t)nc * MROWS + mt * 128 + tid] = redm[0][tid] + redm[1][tid];
}

// ---------------------------------------------------------------------------
// ctx: grid 256. Sum 4 nc score partials, softmax (b_full invariant),
// write alpha, stream context: thread -> one float4 column, 196-pixel loop.
// ---------------------------------------------------------------------------
__global__ __launch_bounds__(512) void bahdanau_ctx(
    const float* __restrict__ enc, const float* __restrict__ spart,
    float* __restrict__ out_ctx, float* __restrict__ out_alpha)
{
    __shared__ float al[256];
    __shared__ float msum[2];
    const int b    = blockIdx.x;
    const int tid  = threadIdx.x;
    const int lane = tid & 63;
    const int wid  = tid >> 6;

    if (tid < NPIX) {
        int row = b * NPIX + tid;
        al[tid] = spart[row] + spart[MROWS + row] + spart[2 * MROWS + row] + spart[3 * MROWS + row];
    } else if (tid < 256) {
        al[tid] = -3.4e38f;
    }
    __syncthreads();

    if (wid == 0) {
        float s0 = al[lane], s1 = al[lane + 64], s2 = al[lane + 128], s3 = al[lane + 192];
        float m = fmaxf(fmaxf(s0, s1), fmaxf(s2, s3));
        #pragma unroll
        for (int d = 1; d <= 32; d <<= 1) m = fmaxf(m, __shfl_xor(m, d));
        float e = __expf(s0 - m) + __expf(s1 - m) + __expf(s2 - m) + __expf(s3 - m);
        #pragma unroll
        for (int d = 1; d <= 32; d <<= 1) e += __shfl_xor(e, d);
        if (lane == 0) { msum[0] = m; msum[1] = e; }
    }
    __syncthreads();
    float m    = msum[0];
    float rinv = 1.f / msum[1];
    if (tid < NPIX) {
        float a = __expf(al[tid] - m) * rinv;
        al[tid] = a;
        out_alpha[b * NPIX + tid] = a;
    }
    __syncthreads();

    float4 c4 = {0.f, 0.f, 0.f, 0.f};
    const float4* enc4 = reinterpret_cast<const float4*>(enc + (size_t)b * NPIX * ENC_DIM);
    #pragma unroll 4
    for (int p = 0; p < NPIX; ++p) {
        float a  = al[p];
        float4 v = enc4[(size_t)p * (ENC_DIM / 4) + tid];
        c4.x += a * v.x; c4.y += a * v.y; c4.z += a * v.z; c4.w += a * v.w;
    }
    reinterpret_cast<float4*>(out_ctx)[(size_t)b * (ENC_DIM / 4) + tid] = c4;
}

extern "C" void kernel_launch(void* const* d_in, const int* in_sizes, int n_in,
                              void* d_out, int out_size, void* d_ws, size_t ws_size,
                              hipStream_t stream) {
    const float* enc    = (const float*)d_in[0];
    const float* dech   = (const float*)d_in[1];
    const float* W_enc  = (const float*)d_in[2];
    const float* b_enc  = (const float*)d_in[3];
    const float* W_dec  = (const float*)d_in[4];
    const float* b_dec  = (const float*)d_in[5];
    const float* w_full = (const float*)d_in[6];
    // d_in[7] = b_full: softmax-invariant, unused.

    float* att2pb = (float*)d_ws;                              // 512 KiB
    short* Wpack  = (short*)((char*)d_ws + 512 * 1024);        // 2 MiB
    float* spart  = (float*)((char*)d_ws + 2560 * 1024);       // 4*50176*4 = 784 KiB

    float* out_ctx   = (float*)d_out;
    float* out_alpha = out_ctx + (size_t)BATCH * ENC_DIM;

    bahdanau_prep<<<768, 256, 0, stream>>>(dech, W_enc, b_enc, W_dec, b_dec, att2pb, Wpack);
    bahdanau_gemm<<<1568, 256, 0, stream>>>(enc, w_full, att2pb, Wpack, spart);
    bahdanau_ctx<<<BATCH, 512, 0, stream>>>(enc, spart, out_ctx, out_alpha);
}